// Round 5
// baseline (353.629 us; speedup 1.0000x reference)
//
#include <hip/hip_runtime.h>

// GCN layer on MI355X — round 5.
//   prep_zero:      Wsw (bf16 MFMA-B swizzle), permuted BN scale/shift/bias,
//                   cur=0
//   degree_count:   histogram of dst (1.6M int atomics, ~20us)  [un-fused:
//                   r4 fusion measured worthless — serial anyway]
//   linear_mfma:    h' = bf16(x@W+b), canonical LDS-staged MFMA GEMM.
//                   h stored COLUMN-PERMUTED: c' = m*8+nt, so each lane's 8
//                   accumulator cols pack into one bf16x8 -> coalesced 16B
//                   stores (r4: 2B scattered shorts, latency-bound 93us).
//   scan1/scan3m:   exclusive scan -> off (+cursor copy)
//   csr_fill_part:  XCD-partitioned fill (r4 win, kept)
//   gather_bn_relu: out = relu(BN(mean(h'[csr[dst]]))); BN consts permuted,
//                   epilogue un-permutes via wave-private LDS -> coalesced out.
// mean(h[src]) = mean(x[src])@W + b (linearity); deg=0 -> sum=0 -> relu(sh).

#define NN 100000
#define NE 1600000
#define CC 128
#define BN_EPS 1e-5f
#define NB 391        // ceil(NN/256)
#define LBLK 1563     // ceil(NN/64) linear blocks
#define FCHUNKS 256   // csr_fill chunks per partition
#define FCHUNK 6250   // 256*6250 = NE
#define PARTN 12500   // NN/8 dst nodes per XCD partition
#define LSTR 136      // LDS row stride in bf16 (128 + 8 pad)

typedef __attribute__((ext_vector_type(8))) short bf16x8;
typedef __attribute__((ext_vector_type(4))) float f32x4;

static __device__ __forceinline__ short f2bf(float f) {
  union { float f; unsigned u; } v; v.f = f;
  unsigned r = (v.u + 0x7FFF + ((v.u >> 16) & 1)) >> 16;  // RNE
  return (short)r;
}
static __device__ __forceinline__ float bflo(unsigned p) {
  return __uint_as_float(p << 16);
}
static __device__ __forceinline__ float bfhi(unsigned p) {
  return __uint_as_float(p & 0xffff0000u);
}

// ---------------------------------------------------------------------------
// prep_zero: zero cursor, swizzle W into bf16 B-fragments, and write BN
// scale/shift/bias in the PERMUTED channel order c' = m*8+nt (orig = nt*16+m,
// i.e. orig(c') = (c'&7)*16 + (c'>>3)) used by h'.
// B-frag (16x16x32): lane = (n&15) + 16*quad holds B[kb*32+quad*8+j][n].
// ---------------------------------------------------------------------------
__global__ __launch_bounds__(256) void prep_zero(
    const float* __restrict__ W, const float* __restrict__ bias,
    const float* __restrict__ gamma, const float* __restrict__ beta,
    const float* __restrict__ rmean, const float* __restrict__ rvar,
    short* __restrict__ Wsw, float* __restrict__ scshP,
    int* __restrict__ cur) {
  const int i = blockIdx.x * 256 + threadIdx.x;
  if (i < NN) cur[i] = 0;
  if (i < CC * CC) {
    int k = i >> 7, n = i & 127;
    int nt = n >> 4, kb = k >> 5, q = (k >> 3) & 3, j = k & 7;
    int lane = (n & 15) + 16 * q;
    Wsw[(size_t)(((nt * 4 + kb) * 64 + lane) * 8 + j)] = f2bf(W[i]);
  }
  if (i < CC) {
    const int o = (i & 7) * 16 + (i >> 3);  // orig channel for c'=i
    float sc = gamma[o] * rsqrtf(rvar[o] + BN_EPS);
    scshP[i] = sc;
    scshP[CC + i] = beta[o] - rmean[o] * sc;
    scshP[2 * CC + i] = bias[o];
  }
}

// ---------------------------------------------------------------------------
// degree_count: 1.6M int atomics.
// ---------------------------------------------------------------------------
__global__ __launch_bounds__(256) void degree_count(const int* __restrict__ ei,
                                                    int* __restrict__ cnt) {
  int e = blockIdx.x * 256 + threadIdx.x;
  if (e >= NE) return;
  atomicAdd(cnt + ei[NE + e], 1);
}

// ---------------------------------------------------------------------------
// linear_mfma: h' = bf16(x@W+b), 64 rows/block, 4 waves x 16 rows.
// Stage 1: coalesced float4 global loads -> bf16 LDS tile [64][LSTR].
// Stage 2: ds_read_b128 A-frags (8-way bank spread = b128 optimum),
//          B-frags from Wsw (L1-resident).
// Epilogue: permuted pack — lane(q,m) holds rows q*4+reg, cols nt*16+m;
//          c' = m*8+nt makes the 8 cols contiguous -> one bf16x8 store/row.
// ---------------------------------------------------------------------------
__global__ __launch_bounds__(256) void linear_mfma(
    const float* __restrict__ x, const short* __restrict__ Wsw,
    const float* __restrict__ scshP, short* __restrict__ hout) {
  __shared__ short lsA[64 * LSTR];  // 17.4 KB
  const int t = threadIdx.x;
  const int n0 = blockIdx.x * 64;

  // Cooperative load: 64 rows x 32 float4 = 2048 float4, 8 iters of 256.
#pragma unroll
  for (int j = 0; j < 8; ++j) {
    const int idx = j * 256 + t;
    const int row = idx >> 5, kc4 = idx & 31;
    float4 v = make_float4(0.f, 0.f, 0.f, 0.f);
    if (n0 + row < NN) v = *(const float4*)(x + (size_t)(n0 + row) * CC + kc4 * 4);
    short4 s;
    s.x = f2bf(v.x); s.y = f2bf(v.y); s.z = f2bf(v.z); s.w = f2bf(v.w);
    *(short4*)(lsA + row * LSTR + kc4 * 4) = s;
  }
  __syncthreads();

  const int wave = t >> 6, lane = t & 63;
  const int quad = lane >> 4, m = lane & 15;
  const int rowbase = n0 + wave * 16;

  f32x4 acc[8];
#pragma unroll
  for (int nt = 0; nt < 8; ++nt) acc[nt] = (f32x4){0.f, 0.f, 0.f, 0.f};

#pragma unroll
  for (int kb = 0; kb < 4; ++kb) {
    const bf16x8 a =
        *(const bf16x8*)(lsA + (wave * 16 + m) * LSTR + kb * 32 + quad * 8);
#pragma unroll
    for (int nt = 0; nt < 8; ++nt) {
      bf16x8 b = *(const bf16x8*)(Wsw + (size_t)(((nt * 4 + kb) * 64 + lane) * 8));
      acc[nt] = __builtin_amdgcn_mfma_f32_16x16x32_bf16(a, b, acc[nt], 0, 0, 0);
    }
  }

  // biasP is permuted: biasP[m*8+nt] = bias[nt*16+m] -> contiguous float4x2.
  const float4 b0 = *(const float4*)(scshP + 2 * CC + m * 8);
  const float4 b1 = *(const float4*)(scshP + 2 * CC + m * 8 + 4);
  const float bv[8] = {b0.x, b0.y, b0.z, b0.w, b1.x, b1.y, b1.z, b1.w};

#pragma unroll
  for (int reg = 0; reg < 4; ++reg) {
    const int R = rowbase + quad * 4 + reg;
    if (R >= NN) continue;
    bf16x8 hv;
#pragma unroll
    for (int nt = 0; nt < 8; ++nt) hv[nt] = f2bf(acc[nt][reg] + bv[nt]);
    *(bf16x8*)(hout + (size_t)R * CC + m * 8) = hv;  // coalesced 16B/lane
  }
}

// ---------------------------------------------------------------------------
// scan1: per-block inclusive scan -> exclusive off + block totals.
// scan3m: each block reduces bsum prefix itself, writes off + cursor copy.
// ---------------------------------------------------------------------------
__global__ __launch_bounds__(256) void scan1(const int* __restrict__ cnt,
                                             int* __restrict__ off,
                                             int* __restrict__ bsum) {
  __shared__ int sh[256];
  const int t = threadIdx.x;
  const int i = blockIdx.x * 256 + t;
  const int v = (i < NN) ? cnt[i] : 0;
  sh[t] = v;
  __syncthreads();
  for (int d = 1; d < 256; d <<= 1) {
    int add = (t >= d) ? sh[t - d] : 0;
    __syncthreads();
    sh[t] += add;
    __syncthreads();
  }
  if (i < NN) off[i] = sh[t] - v;
  if (t == 255) bsum[blockIdx.x] = sh[t];
}

__global__ __launch_bounds__(256) void scan3m(int* __restrict__ off,
                                              const int* __restrict__ bsum,
                                              int* __restrict__ cur) {
  __shared__ int sh[256];
  const int b = blockIdx.x, t = threadIdx.x;
  int s = 0;
  for (int j = t; j < b; j += 256) s += bsum[j];
  sh[t] = s;
  __syncthreads();
  for (int d = 128; d > 0; d >>= 1) {
    if (t < d) sh[t] += sh[t + d];
    __syncthreads();
  }
  const int pref = sh[0];
  const int i = b * 256 + t;
  if (i < NN) {
    int o = off[i] + pref;
    off[i] = o;
    cur[i] = o;
  }
  if (i == 0) off[NN] = NE;
}

// ---------------------------------------------------------------------------
// csr_fill, XCD-partitioned (r4 win: csr lines fill in one XCD's L2).
// ---------------------------------------------------------------------------
__global__ __launch_bounds__(256) void csr_fill_part(
    const int* __restrict__ ei, int* __restrict__ cursor,
    int* __restrict__ csr) {
  const int p = blockIdx.x & 7;
  const int c = blockIdx.x >> 3;
  const int lo = p * PARTN, hi = lo + PARTN;
  const int e0 = c * FCHUNK;
  const int e1 = e0 + FCHUNK;
  for (int e = e0 + threadIdx.x; e < e1; e += 256) {
    int dst = ei[NE + e];
    if (dst >= lo && dst < hi) {
      int pos = atomicAdd(cursor + dst, 1);
      csr[pos] = ei[e];
    }
  }
}

// ---------------------------------------------------------------------------
// gather_bn_relu on permuted h': lane owns c'=(2l,2l+1); BN consts permuted.
// Epilogue un-permutes through a wave-private 512B LDS slab so out keeps
// original channel order with coalesced float2 stores.
// ---------------------------------------------------------------------------
__global__ __launch_bounds__(256) void gather_bn_relu(
    const short* __restrict__ h, const int* __restrict__ off,
    const int* __restrict__ csr, const float* __restrict__ scshP,
    float* __restrict__ out) {
  __shared__ float uns[4][CC];
  const int node = (blockIdx.x * 256 + threadIdx.x) >> 6;
  const int w = threadIdx.x >> 6;
  const int lane = threadIdx.x & 63;
  if (node >= NN) return;
  const int s = off[node], e = off[node + 1];
  const unsigned* hb = (const unsigned*)h;

  float ax = 0.f, ay = 0.f;
  int i = s;
  for (; i + 3 < e; i += 4) {
    int s0 = csr[i], s1 = csr[i + 1], s2 = csr[i + 2], s3 = csr[i + 3];
    unsigned p0 = hb[(size_t)s0 * 64 + lane];
    unsigned p1 = hb[(size_t)s1 * 64 + lane];
    unsigned p2 = hb[(size_t)s2 * 64 + lane];
    unsigned p3 = hb[(size_t)s3 * 64 + lane];
    ax += (bflo(p0) + bflo(p1)) + (bflo(p2) + bflo(p3));
    ay += (bfhi(p0) + bfhi(p1)) + (bfhi(p2) + bfhi(p3));
  }
  for (; i < e; ++i) {
    unsigned p = hb[(size_t)csr[i] * 64 + lane];
    ax += bflo(p);
    ay += bfhi(p);
  }
  const float inv = (e > s) ? 1.0f / (float)(e - s) : 0.0f;
  const float2 sc = *(const float2*)(scshP + 2 * lane);
  const float2 sh = *(const float2*)(scshP + CC + 2 * lane);
  // orig channel for c'=2l is ((2l)&7)*16 + (l>>2); c'=2l+1 is +16.
  const int o0 = ((2 * lane) & 7) * 16 + (lane >> 2);
  uns[w][o0] = fmaxf(0.f, ax * inv * sc.x + sh.x);
  uns[w][o0 + 16] = fmaxf(0.f, ay * inv * sc.y + sh.y);
  // wave-private slab: no barrier needed, compiler orders via lgkmcnt.
  const float2 v = *(const float2*)(&uns[w][2 * lane]);
  *(float2*)(out + (size_t)node * CC + lane * 2) = v;
}

// ---------------------------------------------------------------------------
// Fallback (small ws): atomic scatter + fp32 vector GEMM.
// ---------------------------------------------------------------------------
__global__ __launch_bounds__(256) void edge_scatter(
    const float* __restrict__ x, const int* __restrict__ ei,
    float* __restrict__ sums, int* __restrict__ cnt) {
  int gt = blockIdx.x * 256 + threadIdx.x;
  int e = gt >> 5;
  int sub = gt & 31;
  if (e >= NE) return;
  int src = ei[e];
  int dst = ei[NE + e];
  const float4 v = *(const float4*)(x + (size_t)src * CC + sub * 4);
  float* o = sums + (size_t)dst * CC + sub * 4;
  unsafeAtomicAdd(o + 0, v.x);
  unsafeAtomicAdd(o + 1, v.y);
  unsafeAtomicAdd(o + 2, v.z);
  unsafeAtomicAdd(o + 3, v.w);
  if (sub == 0) atomicAdd(cnt + dst, 1);
}

__global__ __launch_bounds__(256) void gemm_bn_relu_fb(
    float* buf, const float* __restrict__ W, const float* __restrict__ bias,
    const float* __restrict__ gamma, const float* __restrict__ beta,
    const float* __restrict__ rmean, const float* __restrict__ rvar,
    const int* __restrict__ cnt) {
  __shared__ float xsT[CC][65];
  const int t = threadIdx.x;
  const int n0 = blockIdx.x * 64;
  for (int j = 0; j < 8; ++j) {
    int i = t + 256 * j;
    int row = i >> 5;
    int ko = (i & 31) * 4;
    float4 v = make_float4(0.f, 0.f, 0.f, 0.f);
    if (n0 + row < NN) v = *(const float4*)(buf + (size_t)(n0 + row) * CC + ko);
    xsT[ko + 0][row] = v.x;
    xsT[ko + 1][row] = v.y;
    xsT[ko + 2][row] = v.z;
    xsT[ko + 3][row] = v.w;
  }
  __syncthreads();
  const int cg = t & 31;
  const int ng8 = (t >> 5) * 8;
  float acc[8][4];
#pragma unroll
  for (int j = 0; j < 8; ++j)
#pragma unroll
    for (int c = 0; c < 4; ++c) acc[j][c] = 0.f;
#pragma unroll 8
  for (int k = 0; k < CC; ++k) {
    const float4 wv = *(const float4*)(W + k * CC + cg * 4);
#pragma unroll
    for (int j = 0; j < 8; ++j) {
      const float xv = xsT[k][ng8 + j];
      acc[j][0] = fmaf(xv, wv.x, acc[j][0]);
      acc[j][1] = fmaf(xv, wv.y, acc[j][1]);
      acc[j][2] = fmaf(xv, wv.z, acc[j][2]);
      acc[j][3] = fmaf(xv, wv.w, acc[j][3]);
    }
  }
  const float4 bb = *(const float4*)(bias + cg * 4);
  const float4 gg = *(const float4*)(gamma + cg * 4);
  const float4 bt = *(const float4*)(beta + cg * 4);
  const float4 mu = *(const float4*)(rmean + cg * 4);
  const float4 vr = *(const float4*)(rvar + cg * 4);
  float sc[4], sh[4];
  sc[0] = gg.x * rsqrtf(vr.x + BN_EPS);
  sc[1] = gg.y * rsqrtf(vr.y + BN_EPS);
  sc[2] = gg.z * rsqrtf(vr.z + BN_EPS);
  sc[3] = gg.w * rsqrtf(vr.w + BN_EPS);
  sh[0] = bt.x - mu.x * sc[0];
  sh[1] = bt.y - mu.y * sc[1];
  sh[2] = bt.z - mu.z * sc[2];
  sh[3] = bt.w - mu.w * sc[3];
#pragma unroll
  for (int j = 0; j < 8; ++j) {
    const int n = n0 + ng8 + j;
    if (n >= NN) continue;
    const int cn = cnt[n];
    const float inv = cn > 0 ? 1.0f / (float)cn : 0.0f;
    const float bsel = cn > 0 ? 1.0f : 0.0f;
    float4 o;
    o.x = fmaxf(0.f, (acc[j][0] * inv + bsel * bb.x) * sc[0] + sh[0]);
    o.y = fmaxf(0.f, (acc[j][1] * inv + bsel * bb.y) * sc[1] + sh[1]);
    o.z = fmaxf(0.f, (acc[j][2] * inv + bsel * bb.z) * sc[2] + sh[2]);
    o.w = fmaxf(0.f, (acc[j][3] * inv + bsel * bb.w) * sc[3] + sh[3]);
    *(float4*)(buf + (size_t)n * CC + cg * 4) = o;
  }
}

extern "C" void kernel_launch(void* const* d_in, const int* in_sizes, int n_in,
                              void* d_out, int out_size, void* d_ws, size_t ws_size,
                              hipStream_t stream) {
  const float* x     = (const float*)d_in[0];
  const int*   ei    = (const int*)d_in[1];
  const float* W     = (const float*)d_in[2];
  const float* bias  = (const float*)d_in[3];
  const float* gamma = (const float*)d_in[4];
  const float* beta  = (const float*)d_in[5];
  const float* rmean = (const float*)d_in[6];
  const float* rvar  = (const float*)d_in[7];
  float* out = (float*)d_out;

  // ws layout (bytes): off[NN+1] | cur[NN] | bsum[512] | csr[NE] | scshP[512f]
  //                    | Wsw[16384 bf16] | h[NN*CC bf16]
  const size_t OFF_B  = 0;
  const size_t CUR_B  = 400128;
  const size_t BSUM_B = 800256;
  const size_t CSR_B  = 802304;
  const size_t SCSH_B = 7202304;
  const size_t WSW_B  = 7204352;
  const size_t H_B    = 7237120;
  const size_t NEED   = H_B + (size_t)NN * CC * 2;  // ~32.8 MB

  if (ws_size >= NEED) {
    int*   off   = (int*)((char*)d_ws + OFF_B);
    int*   cur   = (int*)((char*)d_ws + CUR_B);
    int*   bsum  = (int*)((char*)d_ws + BSUM_B);
    int*   csr   = (int*)((char*)d_ws + CSR_B);
    float* scshP = (float*)((char*)d_ws + SCSH_B);
    short* Wsw   = (short*)((char*)d_ws + WSW_B);
    short* h     = (short*)((char*)d_ws + H_B);

    prep_zero<<<NB, 256, 0, stream>>>(W, bias, gamma, beta, rmean, rvar,
                                      Wsw, scshP, cur);
    degree_count<<<(NE + 255) / 256, 256, 0, stream>>>(ei, cur);
    linear_mfma<<<LBLK, 256, 0, stream>>>(x, Wsw, scshP, h);
    scan1<<<NB, 256, 0, stream>>>(cur, off, bsum);
    scan3m<<<NB, 256, 0, stream>>>(off, bsum, cur);
    csr_fill_part<<<FCHUNKS * 8, 256, 0, stream>>>(ei, cur, csr);
    gather_bn_relu<<<(NN * 64 + 255) / 256, 256, 0, stream>>>(h, off, csr,
                                                              scshP, out);
  } else {
    int* cnt = (int*)d_ws;
    hipMemsetAsync(out, 0, (size_t)NN * CC * sizeof(float), stream);
    hipMemsetAsync(cnt, 0, (size_t)NN * sizeof(int), stream);
    edge_scatter<<<(NE * 32) / 256, 256, 0, stream>>>(x, ei, out, cnt);
    gemm_bn_relu_fb<<<(NN + 63) / 64, 256, 0, stream>>>(
        out, W, bias, gamma, beta, rmean, rvar, cnt);
  }
}